// Round 1
// baseline (1883.314 us; speedup 1.0000x reference)
//
#include <hip/hip_runtime.h>
#include <math.h>

__device__ __forceinline__ float siluf(float z) {
    return z / (1.0f + __expf(-z));
}
__device__ __forceinline__ float sigmf(float z) {
    return 1.0f / (1.0f + __expf(-z));
}

// Zero the scatter accumulators in workspace and the pot/vdw output slots.
__global__ __launch_bounds__(256) void k_zero(float* __restrict__ ws,
                                              float* __restrict__ potvdw, int n_ws) {
    int i = blockIdx.x * blockDim.x + threadIdx.x;
    if (i < n_ws) ws[i] = 0.0f;
    if (i < 2) potvdw[i] = 0.0f;
}

// Pass 1: per-edge chi / sigma / eps MLPs (64->16->1, 64->32->1, 64->32->1),
// scatter-add into per-node accumulators.
// TWO threads per edge: parity p handles hidden columns [p*8,(p+1)*8) of chi and
// [p*16,(p+1)*16) of sigma/eps -> 40 live accumulators/thread instead of 80.
// (80 accumulators > 72 arch VGPRs forced AGPR/scratch shuffling: 31% occupancy,
//  33% VALUBusy. 40 fits comfortably.)
__global__ __launch_bounds__(256) void k_edge_pass1(
    const float* __restrict__ x, const int* __restrict__ senders,
    const float* __restrict__ Wc1, const float* __restrict__ Wc2,
    const float* __restrict__ Ws1, const float* __restrict__ Ws2,
    const float* __restrict__ We1, const float* __restrict__ We2,
    float* __restrict__ chis, float* __restrict__ sigr, float* __restrict__ epsr,
    int E)
{
    const int t = blockIdx.x * 256 + threadIdx.x;
    const int e = t >> 1;     // edge index
    const int p = t & 1;      // which half of the hidden units
    if (e >= E) return;

    const float4* x4 = (const float4*)(x + (size_t)e * 64);
    const float* wc1 = Wc1 + p * 8;    // [64,16] row-major, our 8 columns
    const float* ws1 = Ws1 + p * 16;   // [64,32] row-major, our 16 columns
    const float* we1 = We1 + p * 16;

    float hc[8], hs[16], he[16];
    #pragma unroll
    for (int j = 0; j < 8; j++) hc[j] = 0.f;
    #pragma unroll
    for (int j = 0; j < 16; j++) { hs[j] = 0.f; he[j] = 0.f; }

    #pragma unroll 4
    for (int q = 0; q < 16; q++) {
        float4 xv = x4[q];
        float xs[4] = {xv.x, xv.y, xv.z, xv.w};
        #pragma unroll
        for (int t4 = 0; t4 < 4; t4++) {
            const int i = q * 4 + t4;
            const float xi = xs[t4];
            #pragma unroll
            for (int j = 0; j < 8; j++)  hc[j] = fmaf(xi, wc1[i * 16 + j], hc[j]);
            #pragma unroll
            for (int j = 0; j < 16; j++) hs[j] = fmaf(xi, ws1[i * 32 + j], hs[j]);
            #pragma unroll
            for (int j = 0; j < 16; j++) he[j] = fmaf(xi, we1[i * 32 + j], he[j]);
        }
    }

    const float s64 = 0.125f;                 // 1/sqrt(64)
    float chi = 0.f, sg = 0.f, ep = 0.f;
    #pragma unroll
    for (int j = 0; j < 8; j++)  chi = fmaf(siluf(hc[j] * s64), Wc2[p * 8 + j], chi);
    #pragma unroll
    for (int j = 0; j < 16; j++) sg = fmaf(siluf(hs[j] * s64), Ws2[p * 16 + j], sg);
    #pragma unroll
    for (int j = 0; j < 16; j++) ep = fmaf(siluf(he[j] * s64), We2[p * 16 + j], ep);

    // combine the two half-sums within the lane pair
    chi += __shfl_xor(chi, 1, 64);
    sg  += __shfl_xor(sg, 1, 64);
    ep  += __shfl_xor(ep, 1, 64);

    const float s32i = 0.17677669529663687f;   // 1/sqrt(32)
    int s = senders[e];
    if (p == 0) {
        atomicAdd(&chis[s], chi * 0.25f);      // 1/sqrt(16)
        atomicAdd(&sigr[s], sg * s32i);
    } else {
        atomicAdd(&epsr[s], ep * s32i);
    }
}

// Node stage: charges, pot/vdw reductions, charge-conditioned embedding w[n][16].
__global__ __launch_bounds__(256) void k_nodes(
    const float* __restrict__ chis, const float* __restrict__ sigr,
    const float* __restrict__ epsr,
    const int* __restrict__ species, const float* __restrict__ radius,
    const float* __restrict__ hardness, const float* __restrict__ cembed,
    const float* __restrict__ Ww1,
    float* __restrict__ charges_out, float* __restrict__ w_out,
    float* __restrict__ pot_out, float* __restrict__ vdw_out, int N)
{
    int n = blockIdx.x * 256 + threadIdx.x;
    float potc = 0.f, vdwc = 0.f;
    if (n < N) {
        int sp = species[n];
        float chi = chis[n];
        float gam = fmaf(4.f, radius[sp], 0.5f);
        float hd = hardness[sp];
        // numerically stable softplus
        float hard = fmaxf(hd, 0.f) + log1pf(__expf(-fabsf(hd)));
        float q = -chi / hard;
        potc = 0.5f * (hard + 1.f / gam) * q * q + chi * q;
        float sgv = sigmf(sigr[n]) * 0.15f + 0.15f;
        float epv = sigmf(epsr[n]) * 1.7f + 0.3f;
        vdwc = epv * sgv;
        charges_out[n] = q;

        // w = concat([q, cembed[sp]]) @ (Ww1 / sqrt(17));  Ww1 is [17,16] row-major
        float acc[16];
        #pragma unroll
        for (int k = 0; k < 16; k++) acc[k] = q * Ww1[k];
        #pragma unroll
        for (int i = 0; i < 16; i++) {
            float c = cembed[sp * 16 + i];
            #pragma unroll
            for (int k = 0; k < 16; k++) acc[k] = fmaf(c, Ww1[(i + 1) * 16 + k], acc[k]);
        }
        const float s17 = 0.24253562503633297f; // 1/sqrt(17)
        #pragma unroll
        for (int k = 0; k < 16; k++) w_out[n * 16 + k] = acc[k] * s17;
    }
    // wave reduce (64 lanes) then block reduce pot/vdw
    #pragma unroll
    for (int off = 32; off > 0; off >>= 1) {
        potc += __shfl_down(potc, off, 64);
        vdwc += __shfl_down(vdwc, off, 64);
    }
    __shared__ float sp_[4], sv_[4];
    int wid = threadIdx.x >> 6, lid = threadIdx.x & 63;
    if (lid == 0) { sp_[wid] = potc; sv_[wid] = vdwc; }
    __syncthreads();
    if (threadIdx.x == 0) {
        atomicAdd(pot_out, sp_[0] + sp_[1] + sp_[2] + sp_[3]);
        atomicAdd(vdw_out, sv_[0] + sv_[1] + sv_[2] + sv_[3]);
    }
}

// Pass 2: per-edge 3-layer MLP on concat([x, w[sender]]) + envelope, plus V copy.
__global__ __launch_bounds__(256) void k_edge_pass2(
    const float* __restrict__ x, const float* __restrict__ V,
    const float* __restrict__ vectors, const int* __restrict__ senders,
    const float* __restrict__ w_nodes,
    const float* __restrict__ Wx1, const float* __restrict__ Wx2,
    const float* __restrict__ Wx3,
    float* __restrict__ xout, float* __restrict__ Vout, int E)
{
    int e = blockIdx.x * 256 + threadIdx.x;
    if (e >= E) return;

    float a[32];
    #pragma unroll
    for (int j = 0; j < 32; j++) a[j] = 0.f;

    const float4* x4 = (const float4*)(x + (size_t)e * 64);
    #pragma unroll 4
    for (int q = 0; q < 16; q++) {
        float4 xv = x4[q];
        float xs[4] = {xv.x, xv.y, xv.z, xv.w};
        #pragma unroll
        for (int t = 0; t < 4; t++) {
            const int i = q * 4 + t;
            const float xi = xs[t];
            #pragma unroll
            for (int j = 0; j < 32; j++) a[j] = fmaf(xi, Wx1[i * 32 + j], a[j]);
        }
    }
    int s = senders[e];
    const float4* w4 = (const float4*)(w_nodes + (size_t)s * 16);
    #pragma unroll
    for (int q = 0; q < 4; q++) {
        float4 wv = w4[q];
        float wsv[4] = {wv.x, wv.y, wv.z, wv.w};
        #pragma unroll
        for (int t = 0; t < 4; t++) {
            const int i = 64 + q * 4 + t;
            const float wi = wsv[t];
            #pragma unroll
            for (int j = 0; j < 32; j++) a[j] = fmaf(wi, Wx1[i * 32 + j], a[j]);
        }
    }
    const float s80 = 0.11180339887498948f;   // 1/sqrt(80)
    const float s32i = 0.17677669529663687f;  // 1/sqrt(32)

    float h[32];
    #pragma unroll
    for (int j = 0; j < 32; j++) h[j] = siluf(a[j] * s80);

    float b[32];
    #pragma unroll
    for (int j = 0; j < 32; j++) b[j] = 0.f;
    #pragma unroll 4
    for (int i = 0; i < 32; i++) {
        const float hi = h[i];
        #pragma unroll
        for (int j = 0; j < 32; j++) b[j] = fmaf(hi, Wx2[i * 32 + j], b[j]);
    }
    #pragma unroll
    for (int j = 0; j < 32; j++) h[j] = siluf(b[j] * s32i);

    #pragma unroll
    for (int j = 0; j < 32; j++) b[j] = 0.f;
    #pragma unroll 4
    for (int i = 0; i < 32; i++) {
        const float hi = h[i];
        #pragma unroll
        for (int j = 0; j < 32; j++) b[j] = fmaf(hi, Wx3[i * 32 + j], b[j]);
    }

    float vx = vectors[(size_t)e * 3 + 0];
    float vy = vectors[(size_t)e * 3 + 1];
    float vz = vectors[(size_t)e * 3 + 2];
    float u = sqrtf(vx * vx + vy * vy + vz * vz);  // MAX_RADIUS = 1
    float env = 0.f;
    if (u < 1.f) {
        float u2 = u * u, u4 = u2 * u2, u6 = u4 * u2;
        env = 1.f + u6 * (-28.f + u * (48.f - 21.f * u));
    }
    const float scale = env * s32i;  // fold layer-3 1/sqrt(32) into envelope

    float4* xo4 = (float4*)(xout + (size_t)e * 32);
    #pragma unroll
    for (int q = 0; q < 8; q++) {
        xo4[q] = make_float4(scale * b[q * 4 + 0], scale * b[q * 4 + 1],
                             scale * b[q * 4 + 2], scale * b[q * 4 + 3]);
    }
    const float4* V4 = (const float4*)(V + (size_t)e * 16);
    float4* Vo4 = (float4*)(Vout + (size_t)e * 16);
    #pragma unroll
    for (int q = 0; q < 4; q++) Vo4[q] = V4[q];
}

extern "C" void kernel_launch(void* const* d_in, const int* in_sizes, int n_in,
                              void* d_out, int out_size, void* d_ws, size_t ws_size,
                              hipStream_t stream)
{
    const float* vectors  = (const float*)d_in[0];
    const float* x        = (const float*)d_in[1];
    const float* V        = (const float*)d_in[2];
    const int*   senders  = (const int*)d_in[3];
    const int*   species  = (const int*)d_in[4];
    const float* radius   = (const float*)d_in[5];
    const float* hardness = (const float*)d_in[6];
    const float* cembed   = (const float*)d_in[7];
    const float* Wc1 = (const float*)d_in[8];
    const float* Wc2 = (const float*)d_in[9];
    const float* Ws1 = (const float*)d_in[10];
    const float* Ws2 = (const float*)d_in[11];
    const float* We1 = (const float*)d_in[12];
    const float* We2 = (const float*)d_in[13];
    const float* Ww1 = (const float*)d_in[14];
    const float* Wx1 = (const float*)d_in[15];
    const float* Wx2 = (const float*)d_in[16];
    const float* Wx3 = (const float*)d_in[17];

    const int E = in_sizes[3];   // senders length
    const int N = in_sizes[4];   // species length

    float* out         = (float*)d_out;
    float* xout        = out;                       // E*32
    float* Vout        = out + (size_t)E * 32;      // E*16
    float* charges_out = out + (size_t)E * 48;      // N
    float* pot_out     = charges_out + N;           // 1
    // vdw_out = pot_out + 1

    float* ws   = (float*)d_ws;
    float* chis = ws;                // N
    float* sigr = ws + N;            // N
    float* epsr = ws + 2 * (size_t)N;// N
    float* wno  = ws + 3 * (size_t)N;// N*16

    const int nzero = 3 * N;
    k_zero<<<(nzero + 255) / 256, 256, 0, stream>>>(ws, pot_out, nzero);
    // 2 threads per edge -> 128 edges per 256-thread block
    k_edge_pass1<<<(E + 127) / 128, 256, 0, stream>>>(
        x, senders, Wc1, Wc2, Ws1, Ws2, We1, We2, chis, sigr, epsr, E);
    k_nodes<<<(N + 255) / 256, 256, 0, stream>>>(
        chis, sigr, epsr, species, radius, hardness, cembed, Ww1,
        charges_out, wno, pot_out, pot_out + 1, N);
    k_edge_pass2<<<(E + 255) / 256, 256, 0, stream>>>(
        x, V, vectors, senders, wno, Wx1, Wx2, Wx3, xout, Vout, E);
}

// Round 2
// 1202.501 us; speedup vs baseline: 1.5662x; 1.5662x over previous
//
#include <hip/hip_runtime.h>
#include <math.h>

__device__ __forceinline__ float siluf(float z) {
    return z / (1.0f + __expf(-z));
}
__device__ __forceinline__ float sigmf(float z) {
    return 1.0f / (1.0f + __expf(-z));
}

// Zero the scatter accumulators in workspace and the pot/vdw output slots.
__global__ __launch_bounds__(256) void k_zero(float* __restrict__ ws,
                                              float* __restrict__ potvdw, int n_ws) {
    int i = blockIdx.x * blockDim.x + threadIdx.x;
    if (i < n_ws) ws[i] = 0.0f;
    if (i < 2) potvdw[i] = 0.0f;
}

// Pass 1: per-edge chi / sigma / eps MLPs (64->16->1, 64->32->1, 64->32->1),
// scatter-add into per-node accumulators.
// ONE thread per edge (weight addresses stay wave-uniform -> scalar s_load),
// TWO sequential sweeps over x to cap live accumulators at 48 (was 80, which
// overflowed into AGPRs: VALU can't target AGPRs, tripling inner-loop cost).
// Sweep A: hc[16]+hs[32]; sweep B: he[32] (x re-read mostly L2-hits).
__global__ __launch_bounds__(256) void k_edge_pass1(
    const float* __restrict__ x, const int* __restrict__ senders,
    const float* __restrict__ Wc1, const float* __restrict__ Wc2,
    const float* __restrict__ Ws1, const float* __restrict__ Ws2,
    const float* __restrict__ We1, const float* __restrict__ We2,
    float* __restrict__ chis, float* __restrict__ sigr, float* __restrict__ epsr,
    int E)
{
    const int e = blockIdx.x * 256 + threadIdx.x;
    if (e >= E) return;
    const float4* x4 = (const float4*)(x + (size_t)e * 64);

    const float s64 = 0.125f;                  // 1/sqrt(64)
    const float s32i = 0.17677669529663687f;   // 1/sqrt(32)

    // ---- sweep A: chi (16 hidden) + sigma (32 hidden); 48 live accumulators
    float hc[16], hs[32];
    #pragma unroll
    for (int j = 0; j < 16; j++) hc[j] = 0.f;
    #pragma unroll
    for (int j = 0; j < 32; j++) hs[j] = 0.f;

    #pragma unroll 4
    for (int q = 0; q < 16; q++) {
        float4 xv = x4[q];
        float xs[4] = {xv.x, xv.y, xv.z, xv.w};
        #pragma unroll
        for (int t = 0; t < 4; t++) {
            const int i = q * 4 + t;
            const float xi = xs[t];
            #pragma unroll
            for (int j = 0; j < 16; j++) hc[j] = fmaf(xi, Wc1[i * 16 + j], hc[j]);
            #pragma unroll
            for (int j = 0; j < 32; j++) hs[j] = fmaf(xi, Ws1[i * 32 + j], hs[j]);
        }
    }
    float chi = 0.f, sg = 0.f;
    #pragma unroll
    for (int j = 0; j < 16; j++) chi = fmaf(siluf(hc[j] * s64), Wc2[j], chi);
    #pragma unroll
    for (int j = 0; j < 32; j++) sg = fmaf(siluf(hs[j] * s64), Ws2[j], sg);
    chi *= 0.25f;                              // 1/sqrt(16)
    sg *= s32i;

    // ---- sweep B: eps (32 hidden); 32 live accumulators
    float he[32];
    #pragma unroll
    for (int j = 0; j < 32; j++) he[j] = 0.f;

    #pragma unroll 4
    for (int q = 0; q < 16; q++) {
        float4 xv = x4[q];
        float xs[4] = {xv.x, xv.y, xv.z, xv.w};
        #pragma unroll
        for (int t = 0; t < 4; t++) {
            const int i = q * 4 + t;
            const float xi = xs[t];
            #pragma unroll
            for (int j = 0; j < 32; j++) he[j] = fmaf(xi, We1[i * 32 + j], he[j]);
        }
    }
    float ep = 0.f;
    #pragma unroll
    for (int j = 0; j < 32; j++) ep = fmaf(siluf(he[j] * s64), We2[j], ep);
    ep *= s32i;

    int s = senders[e];
    atomicAdd(&chis[s], chi);
    atomicAdd(&sigr[s], sg);
    atomicAdd(&epsr[s], ep);
}

// Node stage: charges, pot/vdw reductions, charge-conditioned embedding w[n][16].
__global__ __launch_bounds__(256) void k_nodes(
    const float* __restrict__ chis, const float* __restrict__ sigr,
    const float* __restrict__ epsr,
    const int* __restrict__ species, const float* __restrict__ radius,
    const float* __restrict__ hardness, const float* __restrict__ cembed,
    const float* __restrict__ Ww1,
    float* __restrict__ charges_out, float* __restrict__ w_out,
    float* __restrict__ pot_out, float* __restrict__ vdw_out, int N)
{
    int n = blockIdx.x * 256 + threadIdx.x;
    float potc = 0.f, vdwc = 0.f;
    if (n < N) {
        int sp = species[n];
        float chi = chis[n];
        float gam = fmaf(4.f, radius[sp], 0.5f);
        float hd = hardness[sp];
        // numerically stable softplus
        float hard = fmaxf(hd, 0.f) + log1pf(__expf(-fabsf(hd)));
        float q = -chi / hard;
        potc = 0.5f * (hard + 1.f / gam) * q * q + chi * q;
        float sgv = sigmf(sigr[n]) * 0.15f + 0.15f;
        float epv = sigmf(epsr[n]) * 1.7f + 0.3f;
        vdwc = epv * sgv;
        charges_out[n] = q;

        // w = concat([q, cembed[sp]]) @ (Ww1 / sqrt(17));  Ww1 is [17,16] row-major
        float acc[16];
        #pragma unroll
        for (int k = 0; k < 16; k++) acc[k] = q * Ww1[k];
        #pragma unroll
        for (int i = 0; i < 16; i++) {
            float c = cembed[sp * 16 + i];
            #pragma unroll
            for (int k = 0; k < 16; k++) acc[k] = fmaf(c, Ww1[(i + 1) * 16 + k], acc[k]);
        }
        const float s17 = 0.24253562503633297f; // 1/sqrt(17)
        #pragma unroll
        for (int k = 0; k < 16; k++) w_out[n * 16 + k] = acc[k] * s17;
    }
    // wave reduce (64 lanes) then block reduce pot/vdw
    #pragma unroll
    for (int off = 32; off > 0; off >>= 1) {
        potc += __shfl_down(potc, off, 64);
        vdwc += __shfl_down(vdwc, off, 64);
    }
    __shared__ float sp_[4], sv_[4];
    int wid = threadIdx.x >> 6, lid = threadIdx.x & 63;
    if (lid == 0) { sp_[wid] = potc; sv_[wid] = vdwc; }
    __syncthreads();
    if (threadIdx.x == 0) {
        atomicAdd(pot_out, sp_[0] + sp_[1] + sp_[2] + sp_[3]);
        atomicAdd(vdw_out, sv_[0] + sv_[1] + sv_[2] + sv_[3]);
    }
}

// Pass 2: per-edge 3-layer MLP on concat([x, w[sender]]) + envelope, plus V copy.
__global__ __launch_bounds__(256) void k_edge_pass2(
    const float* __restrict__ x, const float* __restrict__ V,
    const float* __restrict__ vectors, const int* __restrict__ senders,
    const float* __restrict__ w_nodes,
    const float* __restrict__ Wx1, const float* __restrict__ Wx2,
    const float* __restrict__ Wx3,
    float* __restrict__ xout, float* __restrict__ Vout, int E)
{
    int e = blockIdx.x * 256 + threadIdx.x;
    if (e >= E) return;

    float a[32];
    #pragma unroll
    for (int j = 0; j < 32; j++) a[j] = 0.f;

    const float4* x4 = (const float4*)(x + (size_t)e * 64);
    #pragma unroll 4
    for (int q = 0; q < 16; q++) {
        float4 xv = x4[q];
        float xs[4] = {xv.x, xv.y, xv.z, xv.w};
        #pragma unroll
        for (int t = 0; t < 4; t++) {
            const int i = q * 4 + t;
            const float xi = xs[t];
            #pragma unroll
            for (int j = 0; j < 32; j++) a[j] = fmaf(xi, Wx1[i * 32 + j], a[j]);
        }
    }
    int s = senders[e];
    const float4* w4 = (const float4*)(w_nodes + (size_t)s * 16);
    #pragma unroll
    for (int q = 0; q < 4; q++) {
        float4 wv = w4[q];
        float wsv[4] = {wv.x, wv.y, wv.z, wv.w};
        #pragma unroll
        for (int t = 0; t < 4; t++) {
            const int i = 64 + q * 4 + t;
            const float wi = wsv[t];
            #pragma unroll
            for (int j = 0; j < 32; j++) a[j] = fmaf(wi, Wx1[i * 32 + j], a[j]);
        }
    }
    const float s80 = 0.11180339887498948f;   // 1/sqrt(80)
    const float s32i = 0.17677669529663687f;  // 1/sqrt(32)

    float h[32];
    #pragma unroll
    for (int j = 0; j < 32; j++) h[j] = siluf(a[j] * s80);

    float b[32];
    #pragma unroll
    for (int j = 0; j < 32; j++) b[j] = 0.f;
    #pragma unroll 4
    for (int i = 0; i < 32; i++) {
        const float hi = h[i];
        #pragma unroll
        for (int j = 0; j < 32; j++) b[j] = fmaf(hi, Wx2[i * 32 + j], b[j]);
    }
    #pragma unroll
    for (int j = 0; j < 32; j++) h[j] = siluf(b[j] * s32i);

    #pragma unroll
    for (int j = 0; j < 32; j++) b[j] = 0.f;
    #pragma unroll 4
    for (int i = 0; i < 32; i++) {
        const float hi = h[i];
        #pragma unroll
        for (int j = 0; j < 32; j++) b[j] = fmaf(hi, Wx3[i * 32 + j], b[j]);
    }

    float vx = vectors[(size_t)e * 3 + 0];
    float vy = vectors[(size_t)e * 3 + 1];
    float vz = vectors[(size_t)e * 3 + 2];
    float u = sqrtf(vx * vx + vy * vy + vz * vz);  // MAX_RADIUS = 1
    float env = 0.f;
    if (u < 1.f) {
        float u2 = u * u, u4 = u2 * u2, u6 = u4 * u2;
        env = 1.f + u6 * (-28.f + u * (48.f - 21.f * u));
    }
    const float scale = env * s32i;  // fold layer-3 1/sqrt(32) into envelope

    float4* xo4 = (float4*)(xout + (size_t)e * 32);
    #pragma unroll
    for (int q = 0; q < 8; q++) {
        xo4[q] = make_float4(scale * b[q * 4 + 0], scale * b[q * 4 + 1],
                             scale * b[q * 4 + 2], scale * b[q * 4 + 3]);
    }
    const float4* V4 = (const float4*)(V + (size_t)e * 16);
    float4* Vo4 = (float4*)(Vout + (size_t)e * 16);
    #pragma unroll
    for (int q = 0; q < 4; q++) Vo4[q] = V4[q];
}

extern "C" void kernel_launch(void* const* d_in, const int* in_sizes, int n_in,
                              void* d_out, int out_size, void* d_ws, size_t ws_size,
                              hipStream_t stream)
{
    const float* vectors  = (const float*)d_in[0];
    const float* x        = (const float*)d_in[1];
    const float* V        = (const float*)d_in[2];
    const int*   senders  = (const int*)d_in[3];
    const int*   species  = (const int*)d_in[4];
    const float* radius   = (const float*)d_in[5];
    const float* hardness = (const float*)d_in[6];
    const float* cembed   = (const float*)d_in[7];
    const float* Wc1 = (const float*)d_in[8];
    const float* Wc2 = (const float*)d_in[9];
    const float* Ws1 = (const float*)d_in[10];
    const float* Ws2 = (const float*)d_in[11];
    const float* We1 = (const float*)d_in[12];
    const float* We2 = (const float*)d_in[13];
    const float* Ww1 = (const float*)d_in[14];
    const float* Wx1 = (const float*)d_in[15];
    const float* Wx2 = (const float*)d_in[16];
    const float* Wx3 = (const float*)d_in[17];

    const int E = in_sizes[3];   // senders length
    const int N = in_sizes[4];   // species length

    float* out         = (float*)d_out;
    float* xout        = out;                       // E*32
    float* Vout        = out + (size_t)E * 32;      // E*16
    float* charges_out = out + (size_t)E * 48;      // N
    float* pot_out     = charges_out + N;           // 1
    // vdw_out = pot_out + 1

    float* ws   = (float*)d_ws;
    float* chis = ws;                // N
    float* sigr = ws + N;            // N
    float* epsr = ws + 2 * (size_t)N;// N
    float* wno  = ws + 3 * (size_t)N;// N*16

    const int nzero = 3 * N;
    k_zero<<<(nzero + 255) / 256, 256, 0, stream>>>(ws, pot_out, nzero);
    k_edge_pass1<<<(E + 255) / 256, 256, 0, stream>>>(
        x, senders, Wc1, Wc2, Ws1, Ws2, We1, We2, chis, sigr, epsr, E);
    k_nodes<<<(N + 255) / 256, 256, 0, stream>>>(
        chis, sigr, epsr, species, radius, hardness, cembed, Ww1,
        charges_out, wno, pot_out, pot_out + 1, N);
    k_edge_pass2<<<(E + 255) / 256, 256, 0, stream>>>(
        x, V, vectors, senders, wno, Wx1, Wx2, Wx3, xout, Vout, E);
}